// Round 7
// baseline (523.418 us; speedup 1.0000x reference)
//
#include <hip/hip_runtime.h>
#include <math.h>

// ---------------------------------------------------------------------------
// ImplicitFlowDecoder — R7: LDS diet to <=40 KB -> 4 blocks/CU.
// Patches overlaid in dead columns of the single activation buffer.
// 32x32x16 MFMA, bias-in-accumulator, in-place layers.
// ---------------------------------------------------------------------------

typedef short bf16x8 __attribute__((ext_vector_type(8)));
typedef float f32x16 __attribute__((ext_vector_type(16)));

constexpr int W8 = 64, H8 = 48, W16g = 32, H16g = 24, WF = 512, HF = 384;
constexpr int HWs8 = W8 * H8;      // 3072
constexpr int HWs16 = W16g * H16g; // 768
constexpr int MP = 64;             // points per block (one output row segment)
constexpr int NTH = 256;
constexpr int BPR = WF / MP;                // 8
constexpr int NBLK = 2 * HF * BPR;          // 6144

constexpr int S = 296;      // row stride (ushorts); 148 dwords == 20 mod 32
constexpr int SD = S / 2;   // 148 row stride in dwords

// swizzled bf16 weight offsets in d_ws (elems)
constexpr int OFF_WC = 0;
constexpr int OFF_W1 = 8192;
constexpr int OFF_W2 = 40960;
constexpr int OFF_WP = 73728;
constexpr int OFF_W3 = 90112;
constexpr int OFF_W4 = 122880;
constexpr int OFF_H0 = 155648;   // K padded 260->288
constexpr int OFF_H1 = 229376;
constexpr int OFF_H2 = 262144;
constexpr int SWZ_TOTAL = 270336;

__device__ __forceinline__ unsigned short f2bf(float f) {  // RNE (prep only)
  union { float f; unsigned u; } v; v.f = f;
  unsigned r = (v.u + 0x7fffu + ((v.u >> 16) & 1u)) >> 16;
  return (unsigned short)r;
}
__device__ __forceinline__ float bf2f(unsigned short h) {
  union { unsigned u; float f; } v; v.u = ((unsigned)h) << 16;
  return v.f;
}
#if defined(__has_builtin)
#if __has_builtin(__builtin_amdgcn_cvt_pk_bf16_f32)
#define HAS_PK_BF16 1
#endif
#endif
__device__ __forceinline__ unsigned pack2bf(float a, float b) {
#ifdef HAS_PK_BF16
  typedef __bf16 bf2_t __attribute__((ext_vector_type(2)));
  bf2_t r = __builtin_amdgcn_cvt_pk_bf16_f32(a, b);
  return __builtin_bit_cast(unsigned, r);
#else
  unsigned ua = __builtin_bit_cast(unsigned, a) + 0x8000u;
  unsigned ub = __builtin_bit_cast(unsigned, b) + 0x8000u;
  return __builtin_amdgcn_perm(ub, ua, 0x07060302u);
#endif
}
// gelu via A&S 7.1.26 erf approx (|err| <= 1.5e-7 abs)
__device__ __forceinline__ float gelu_fast(float x) {
  float ax = fabsf(x);
  float z = ax * 0.7071067811865475f;
  float t = __builtin_amdgcn_rcpf(fmaf(0.3275911f, z, 1.0f));
  float poly = fmaf(fmaf(fmaf(fmaf(1.061405429f, t, -1.453152027f), t,
                              1.421413741f), t, -0.284496736f), t, 0.254829592f);
  float y = 1.0f - poly * t * __expf(-z * z);
  return 0.5f * (x + ax * y);
}

// ------------------------------- prep kernel -------------------------------
// A-swizzle for 32x32x16: frag (mt,ks) at (mt*nks+ks)*512;
// lane l elem j = W[k = ks*16 + (l>>5)*8 + j][n = mt*32 + (l&31)]
struct PrepParams { const float* W[9]; unsigned short* ws; };

__global__ void prep_kernel(PrepParams pp) {
  const int K_[9]   = {64, 128, 256, 128, 128, 256, 260, 256, 128};
  const int Kp_[9]  = {64, 128, 256, 128, 128, 256, 288, 256, 128};
  const int N_[9]   = {128, 256, 128, 128, 256, 128, 256, 128, 64};
  const int OFF_[9] = {OFF_WC, OFF_W1, OFF_W2, OFF_WP, OFF_W3, OFF_W4, OFF_H0, OFF_H1, OFF_H2};
  for (int e = blockIdx.x * blockDim.x + threadIdx.x; e < SWZ_TOTAL;
       e += gridDim.x * blockDim.x) {
    int L = 0;
#pragma unroll
    for (int i = 1; i < 9; ++i) if (e >= OFF_[i]) L = i;
    int q = e - OFF_[L];
    int j = q & 7;
    int l = (q >> 3) & 63;
    int r = q >> 9;
    int nks = Kp_[L] >> 4;
    int ks = r % nks;
    int mt = r / nks;
    int n = mt * 32 + (l & 31);
    int k = ks * 16 + ((l >> 5) << 3) + j;
    float v = (k < K_[L]) ? pp.W[L][k * N_[L] + n] : 0.0f;
    pp.ws[e] = f2bf(v);
  }
}

// ------------------------------ main kernel --------------------------------
struct Params {
  const float* feat_s8; const float* feat1_s8; const float* feat_s16;
  const float* ctx_s8;  const float* coarse;
  const float* bc; const float* g1; const float* b1; const float* b2;
  const float* bp; const float* g2; const float* b3; const float* b4;
  const float* h0b; const float* h1b; const float* h2b;
  const float* h3w; const float* h3b;
  const unsigned short* ws;
  float* out;
};

__device__ __forceinline__ void bilin_setup(float g, int Sg, int& i0, int& i1, float& w) {
  float s = (g + 1.0f) * (0.5f * Sg) - 0.5f;
  float f = floorf(s);
  w = s - f;
  int a = (int)f;
  i0 = min(max(a, 0), Sg - 1);
  i1 = min(max(a + 1, 0), Sg - 1);
}

// Patch index remap into buf's dead columns (viewed as float*):
// MAP 0: dword cols [32:64)  of each row  (ushort cols [64:128))  cap 2048 floats
// MAP 1: dword cols [128:144) of each row (ushort cols [256:288)) cap 1024 floats
template<int MAP>
__device__ __forceinline__ int pmap(int n) {
  if (MAP == 0) return ((n >> 5) * SD) + 32 + (n & 31);
  else          return ((n >> 4) * SD) + 128 + (n & 15);
}

// 32x32x16 MFMA layer. MT m-tiles/wave; NT n-tiles (2: both halves, 1: wv&1).
// EP: 0=plain, 1=gelu, 2=relu, 3=gated residual. SYNC: in-place barrier.
template<int MT, int NT, int EP, bool SYNC>
__device__ __forceinline__ void mfma_layer(
    const unsigned short* __restrict__ Wsw,
    const float* __restrict__ bias,
    const unsigned short* actIn, int K,
    unsigned short* actOut,
    const float* __restrict__ gate,
    const unsigned short* res)
{
  const int t = threadIdx.x;
  const int l = t & 63;
  const int wv = t >> 6;
  const int nks = K >> 4;
  const int mt0 = (NT == 2) ? wv * MT : (wv >> 1);
  const int ntb = (NT == 2) ? 0 : (wv & 1);
  const int lh = l >> 5;
  const int ll = l & 31;

  f32x16 acc[MT][NT];
#pragma unroll
  for (int m = 0; m < MT; ++m) {
#pragma unroll
    for (int g = 0; g < 4; ++g) {
      const int f0 = (mt0 + m) * 32 + g * 8 + (lh << 2);
      const float4 bv = *(const float4*)(bias + f0);
#pragma unroll
      for (int nt = 0; nt < NT; ++nt) {
        acc[m][nt][g * 4 + 0] = bv.x; acc[m][nt][g * 4 + 1] = bv.y;
        acc[m][nt][g * 4 + 2] = bv.z; acc[m][nt][g * 4 + 3] = bv.w;
      }
    }
  }

  const unsigned short* bbase = actIn + (ntb * 32 + ll) * S + (lh << 3);
  const unsigned short* abase = Wsw + (size_t)mt0 * nks * 512 + l * 8;

  for (int ks = 0; ks < nks; ++ks) {
    bf16x8 B[NT];
#pragma unroll
    for (int nt = 0; nt < NT; ++nt)
      B[nt] = *(const bf16x8*)(bbase + nt * 32 * S + ks * 16);
#pragma unroll
    for (int m = 0; m < MT; ++m) {
      bf16x8 A = *(const bf16x8*)(abase + (m * nks + ks) * 512);
#pragma unroll
      for (int nt = 0; nt < NT; ++nt)
        acc[m][nt] = __builtin_amdgcn_mfma_f32_32x32x16_bf16(A, B[nt], acc[m][nt], 0, 0, 0);
    }
  }

  if (SYNC) __syncthreads();

#pragma unroll
  for (int m = 0; m < MT; ++m) {
#pragma unroll
    for (int g = 0; g < 4; ++g) {
      const int f0 = (mt0 + m) * 32 + g * 8 + (lh << 2);
      float4 gv;
      if (EP == 3) {
        float4 gg = *(const float4*)(gate + f0);
        gv.x = __builtin_amdgcn_rcpf(1.0f + __expf(-gg.x));
        gv.y = __builtin_amdgcn_rcpf(1.0f + __expf(-gg.y));
        gv.z = __builtin_amdgcn_rcpf(1.0f + __expf(-gg.z));
        gv.w = __builtin_amdgcn_rcpf(1.0f + __expf(-gg.w));
      }
#pragma unroll
      for (int nt = 0; nt < NT; ++nt) {
        const int pt = (ntb + nt) * 32 + ll;
        float v[4];
        v[0] = acc[m][nt][g * 4 + 0]; v[1] = acc[m][nt][g * 4 + 1];
        v[2] = acc[m][nt][g * 4 + 2]; v[3] = acc[m][nt][g * 4 + 3];
        if (EP == 1) {
#pragma unroll
          for (int r = 0; r < 4; ++r) v[r] = gelu_fast(v[r]);
        } else if (EP == 2) {
#pragma unroll
          for (int r = 0; r < 4; ++r) v[r] = fmaxf(v[r], 0.0f);
        } else if (EP == 3) {
          uint2 rv = *(const uint2*)(res + pt * S + f0);
          v[0] = fmaf(gv.x, v[0], bf2f((unsigned short)(rv.x & 0xffffu)));
          v[1] = fmaf(gv.y, v[1], bf2f((unsigned short)(rv.x >> 16)));
          v[2] = fmaf(gv.z, v[2], bf2f((unsigned short)(rv.y & 0xffffu)));
          v[3] = fmaf(gv.w, v[3], bf2f((unsigned short)(rv.y >> 16)));
        }
        uint2 pk;
        pk.x = pack2bf(v[0], v[1]);
        pk.y = pack2bf(v[2], v[3]);
        *(uint2*)(actOut + pt * S + f0) = pk;
      }
    }
  }
}

// stage a y-lerped patch into a remapped region of buf
template<int NCOL, int NCH, int MAP>
__device__ void stage_patch(const float* __restrict__ fm, int HW, int Wimg,
                            int base, int y0, int y1, float wy, float* bufF)
{
  const int items = NCOL * NCH;
  for (int e = threadIdx.x; e < items; e += NTH) {
    int ch = e / NCOL, col = e - ch * NCOL;
    int ca = min(base + col, Wimg - 1);
    const float* pp = fm + ch * HW;
    float v0 = pp[y0 * Wimg + ca];
    float v1 = pp[y1 * Wimg + ca];
    bufF[pmap<MAP>(col * (NCH + 2) + ch)] = fmaf(wy, v1 - v0, v0);
  }
}

// x-lerp from remapped patch into bf16 B-layout columns of buf
template<int PAIRS, int MAP, int CST>
__device__ void xlerp_tile(const float* __restrict__ bufF, const int* pcB, int shift,
                           const float* wxA, unsigned short* outBuf, int colOff)
{
  const int items = MP * PAIRS;
  for (int it = threadIdx.x; it < items; it += NTH) {
    int pr = it & (PAIRS - 1);
    int pt = it / PAIRS;
    int pc = pcB[pt] >> shift;
    int c0 = pc & 15, c1 = (pc >> 4) & 15;
    float wx = wxA[pt];
    float2 a = *(const float2*)(bufF + pmap<MAP>(c0 * CST + pr * 2));
    float2 b = *(const float2*)(bufF + pmap<MAP>(c1 * CST + pr * 2));
    float r0 = fmaf(wx, b.x - a.x, a.x);
    float r1 = fmaf(wx, b.y - a.y, a.y);
    *(unsigned*)(outBuf + pt * S + colOff + pr * 2) = pack2bf(r0, r1);
  }
}

// gather-based bilinear (warped sample only)
__device__ void gather_tile(const float* __restrict__ fm, int C, int HW,
    const short* offs, const float* wxA, const float* wyA,
    unsigned short* outBuf, int colOff)
{
  const int items = MP * (C >> 1);
  for (int it = threadIdx.x; it < items; it += NTH) {
    int i = it & (MP - 1);
    int c2 = it >> 6;
    int o00 = offs[0 * MP + i], o01 = offs[1 * MP + i];
    int o10 = offs[2 * MP + i], o11 = offs[3 * MP + i];
    float wx = wxA[i], wy = wyA[i];
    const float* p0 = fm + (c2 * 2) * HW;
    const float* p1 = p0 + HW;
    float a0 = p0[o00], a1 = p0[o01], a2 = p0[o10], a3 = p0[o11];
    float b0 = p1[o00], b1 = p1[o01], b2 = p1[o10], b3 = p1[o11];
    float ax0 = fmaf(wx, a1 - a0, a0), ax1 = fmaf(wx, a3 - a2, a2);
    float bx0 = fmaf(wx, b1 - b0, b0), bx1 = fmaf(wx, b3 - b2, b2);
    float r0 = fmaf(wy, ax1 - ax0, ax0);
    float r1 = fmaf(wy, bx1 - bx0, bx0);
    *(unsigned*)(outBuf + i * S + colOff + c2 * 2) = pack2bf(r0, r1);
  }
}

__global__ __launch_bounds__(256, 4)
void ifd_kernel(Params p)
{
  __shared__ __align__(16) unsigned short buf[MP * S];   // 37888 B
  __shared__ short offsW[4 * MP];                         // 512 B
  __shared__ int pcBoth[MP];                              // 256 B (nibble-packed)
  __shared__ float w8x[MP], w16x[MP], wWx[MP], wWy[MP];   // 1024 B
  __shared__ float caxA[MP], cayA[MP];                    // 512 B
  __shared__ int uy8_0, uy8_1, uy16_0, uy16_1, ubase8, ubase16;
  __shared__ float uwy8, uwy16;                           // 32 B

  float* bufF = (float*)buf;

  const int blk = blockIdx.x;
  const int bb = blk / (HF * BPR);
  const int r = blk % (HF * BPR);
  const int y = r >> 3;
  const int xb = (r & (BPR - 1)) * MP;
  const int t = threadIdx.x;
  const float lim = 1.0f - 1e-6f;

  if (t < MP) {
    const int i = t;
    const int x = xb + i;
    float gx = (x + 0.5f) * (2.0f / WF) - 1.0f;
    float gy = (y + 0.5f) * (2.0f / HF) - 1.0f;
    gx = fminf(fmaxf(gx, -lim), lim);
    gy = fminf(fmaxf(gy, -lim), lim);

    float gx0 = fminf(fmaxf((xb + 0.5f) * (2.0f / WF) - 1.0f, -lim), lim);
    int base8 = min(max((int)floorf((gx0 + 1.0f) * 32.0f - 0.5f), 0), W8 - 1);
    int base16 = min(max((int)floorf((gx0 + 1.0f) * 16.0f - 0.5f), 0), W16g - 1);

    int x0, x1, y0, y1; float wx, wy;
    bilin_setup(gx, W8, x0, x1, wx);
    bilin_setup(gy, H8, y0, y1, wy);
    w8x[i] = wx;
    int o00 = y0 * W8 + x0, o01 = y0 * W8 + x1;
    int o10 = y1 * W8 + x0, o11 = y1 * W8 + x1;

    int a0, a1, b0i, b1i; float vx, vy;
    bilin_setup(gx, W16g, a0, a1, vx);
    bilin_setup(gy, H16g, b0i, b1i, vy);
    w16x[i] = vx;
    pcBoth[i] = (x0 - base8) | ((x1 - base8) << 4)
              | ((a0 - base16) << 8) | ((a1 - base16) << 12);

    if (i == 0) {
      uy8_0 = y0; uy8_1 = y1; uwy8 = wy;
      uy16_0 = b0i; uy16_1 = b1i; uwy16 = vy;
      ubase8 = base8; ubase16 = base16;
    }

    const float* cf = p.coarse + bb * 2 * HWs8;
    float c00 = cf[o00], c01 = cf[o01], c10 = cf[o10], c11 = cf[o11];
    float cx0 = fmaf(wx, c01 - c00, c00), cx1 = fmaf(wx, c11 - c10, c10);
    float cfx = fmaf(wy, cx1 - cx0, cx0);
    const float* cf2 = cf + HWs8;
    c00 = cf2[o00]; c01 = cf2[o01]; c10 = cf2[o10]; c11 = cf2[o11];
    cx0 = fmaf(wx, c01 - c00, c00); cx1 = fmaf(wx, c11 - c10, c10);
    float cfy = fmaf(wy, cx1 - cx0, cx0);
    float cax = cfx * 8.0f, cay = cfy * 8.0f;
    caxA[i] = cax; cayA[i] = cay;

    float wxn = gx + cax * (2.0f / WF);
    float wyn = gy + cay * (2.0f / HF);
    wxn = fminf(fmaxf(wxn, -lim), lim);
    wyn = fminf(fmaxf(wyn, -lim), lim);
    int u0, u1, v0, v1; float uw, vw;
    bilin_setup(wxn, W8, u0, u1, uw);
    bilin_setup(wyn, H8, v0, v1, vw);
    offsW[0 * MP + i] = (short)(v0 * W8 + u0);
    offsW[1 * MP + i] = (short)(v0 * W8 + u1);
    offsW[2 * MP + i] = (short)(v1 * W8 + u0);
    offsW[3 * MP + i] = (short)(v1 * W8 + u1);
    wWx[i] = uw; wWy[i] = vw;
  }
  __syncthreads();

  // stage f8 -> MAP0 (ushort cols [64:128)); ctx -> MAP1 (ushort cols [256:288))
  stage_patch<10, 128, 0>(p.feat_s8 + bb * 128 * HWs8, HWs8, W8,
                          ubase8, uy8_0, uy8_1, uwy8, bufF);
  stage_patch<10, 64, 1>(p.ctx_s8 + bb * 64 * HWs8, HWs8, W8,
                         ubase8, uy8_0, uy8_1, uwy8, bufF);
  __syncthreads();
  xlerp_tile<64, 0, 130>(bufF, pcBoth, 0, w8x, buf, 128);  // f8  -> [128:256)
  xlerp_tile<32, 1, 66>(bufF, pcBoth, 0, w8x, buf, 0);     // ctx -> [0:64)
  __syncthreads();

  // Wc: [0:64) K=64 -> [128:256), residual same cols (per-thread RAW ok)
  mfma_layer<1, 2, 3, false>(p.ws + OFF_WC, p.bc, buf, 64, buf + 128, p.g1, buf + 128);
  // overlap: stage f16 patch -> MAP1 (ctx patch dead; disjoint from Wc's cols)
  stage_patch<6, 128, 1>(p.feat_s16 + bb * 128 * HWs16, HWs16, W16g,
                         ubase16, uy16_0, uy16_1, uwy16, bufF);
  __syncthreads();
  // W1: [128:256) K=128 -> [0:256)   (SYNC)
  mfma_layer<2, 2, 1, true>(p.ws + OFF_W1, p.b1, buf + 128, 128, buf, nullptr, nullptr);
  __syncthreads();
  // W2: [0:256) K=256 -> [0:128)     (SYNC); then f16 x-lerp -> [128:256)
  mfma_layer<1, 2, 0, true>(p.ws + OFF_W2, p.b2, buf, 256, buf, nullptr, nullptr);
  xlerp_tile<64, 1, 130>(bufF, pcBoth, 8, w16x, buf, 128);
  __syncthreads();
  // Wp: [0:128) -> [128:256), residual same cols
  mfma_layer<1, 2, 3, false>(p.ws + OFF_WP, p.bp, buf, 128, buf + 128, p.g2, buf + 128);
  __syncthreads();
  // W3: [128:256) K=128 -> [0:256)   (SYNC)
  mfma_layer<2, 2, 1, true>(p.ws + OFF_W3, p.b3, buf + 128, 128, buf, nullptr, nullptr);
  __syncthreads();
  // W4: [0:256) K=256 -> [0:128)     (SYNC); gather -> [128:256); extras -> [256:288)
  mfma_layer<1, 2, 0, true>(p.ws + OFF_W4, p.b4, buf, 256, buf, nullptr, nullptr);
  gather_tile(p.feat1_s8 + bb * 128 * HWs8, 128, HWs8, offsW, wWx, wWy, buf, 128);
  for (int idx = t; idx < MP * 16; idx += NTH) {
    int row = idx >> 4, c = idx & 15;
    unsigned val = 0;
    if (c == 0) {
      float gx = fminf(fmaxf((xb + row + 0.5f) * (2.0f / WF) - 1.0f, -lim), lim);
      float gy = fminf(fmaxf((y + 0.5f) * (2.0f / HF) - 1.0f, -lim), lim);
      val = pack2bf(gx, gy);
    } else if (c == 1) {
      val = pack2bf(caxA[row] * (1.0f / WF), cayA[row] * (1.0f / HF));
    }
    *(unsigned*)(buf + row * S + 256 + c * 2) = val;
  }
  __syncthreads();
  // flow head, all in-place
  mfma_layer<2, 2, 2, true>(p.ws + OFF_H0, p.h0b, buf, 288, buf, nullptr, nullptr);
  __syncthreads();
  mfma_layer<1, 2, 2, true>(p.ws + OFF_H1, p.h1b, buf, 256, buf, nullptr, nullptr);
  __syncthreads();
  mfma_layer<1, 1, 2, true>(p.ws + OFF_H2, p.h2b, buf, 128, buf, nullptr, nullptr);
  __syncthreads();

  // final 64->2 + output (fp32); h3w from global (L2-hot)
  if (t < 128) {
    int i = t & 63, comp = t >> 6;
    float acc = p.h3b[comp];
    const unsigned short* rowp = buf + i * S;
    const float* wp = p.h3w + comp;
#pragma unroll
    for (int k8 = 0; k8 < 8; ++k8) {
      uint4 av = *(const uint4*)(rowp + k8 * 8);
      const float* w8p = wp + k8 * 16;
      unsigned u0 = av.x, u1 = av.y, u2 = av.z, u3 = av.w;
      acc = fmaf(__builtin_bit_cast(float, u0 << 16),          w8p[0], acc);
      acc = fmaf(__builtin_bit_cast(float, u0 & 0xffff0000u),  w8p[2], acc);
      acc = fmaf(__builtin_bit_cast(float, u1 << 16),          w8p[4], acc);
      acc = fmaf(__builtin_bit_cast(float, u1 & 0xffff0000u),  w8p[6], acc);
      acc = fmaf(__builtin_bit_cast(float, u2 << 16),          w8p[8], acc);
      acc = fmaf(__builtin_bit_cast(float, u2 & 0xffff0000u),  w8p[10], acc);
      acc = fmaf(__builtin_bit_cast(float, u3 << 16),          w8p[12], acc);
      acc = fmaf(__builtin_bit_cast(float, u3 & 0xffff0000u),  w8p[14], acc);
    }
    float flow = (comp ? cayA[i] : caxA[i]) + acc * (comp ? (float)HF : (float)WF);
    p.out[((bb * 2 + comp) * HF + y) * WF + xb + i] = flow;
  }
}

extern "C" void kernel_launch(void* const* d_in, const int* in_sizes, int n_in,
                              void* d_out, int out_size, void* d_ws, size_t ws_size,
                              hipStream_t stream) {
  PrepParams pp;
  pp.W[0] = (const float*)d_in[6];   // Wc
  pp.W[1] = (const float*)d_in[9];   // W1
  pp.W[2] = (const float*)d_in[11];  // W2
  pp.W[3] = (const float*)d_in[13];  // Wp
  pp.W[4] = (const float*)d_in[16];  // W3
  pp.W[5] = (const float*)d_in[18];  // W4
  pp.W[6] = (const float*)d_in[20];  // hw0
  pp.W[7] = (const float*)d_in[22];  // hw1
  pp.W[8] = (const float*)d_in[24];  // hw2
  pp.ws = (unsigned short*)d_ws;
  hipLaunchKernelGGL(prep_kernel, dim3((SWZ_TOTAL + NTH - 1) / NTH), dim3(NTH), 0, stream, pp);

  Params p;
  p.feat_s8  = (const float*)d_in[1];
  p.feat1_s8 = (const float*)d_in[2];
  p.feat_s16 = (const float*)d_in[3];
  p.ctx_s8   = (const float*)d_in[4];
  p.coarse   = (const float*)d_in[5];
  p.bc  = (const float*)d_in[7];
  p.g1  = (const float*)d_in[8];
  p.b1  = (const float*)d_in[10];
  p.b2  = (const float*)d_in[12];
  p.bp  = (const float*)d_in[14];
  p.g2  = (const float*)d_in[15];
  p.b3  = (const float*)d_in[17];
  p.b4  = (const float*)d_in[19];
  p.h0b = (const float*)d_in[21];
  p.h1b = (const float*)d_in[23];
  p.h2b = (const float*)d_in[25];
  p.h3w = (const float*)d_in[26];
  p.h3b = (const float*)d_in[27];
  p.ws  = (const unsigned short*)d_ws;
  p.out = (float*)d_out;

  hipLaunchKernelGGL(ifd_kernel, dim3(NBLK), dim3(NTH), 0, stream, p);
}

// Round 8
// 478.157 us; speedup vs baseline: 1.0947x; 1.0947x over previous
//
#include <hip/hip_runtime.h>
#include <math.h>

// ---------------------------------------------------------------------------
// ImplicitFlowDecoder — R8: coalesced warped gather via per-launch transposed
// bf16 feat1 ([B][H][W][C] in d_ws), K templatized (full unroll).
// 32x32x16 MFMA, bias-in-accumulator, in-place single-buffer LDS, 4 blocks/CU.
// ---------------------------------------------------------------------------

typedef short bf16x8 __attribute__((ext_vector_type(8)));
typedef float f32x16 __attribute__((ext_vector_type(16)));

constexpr int W8 = 64, H8 = 48, W16g = 32, H16g = 24, WF = 512, HF = 384;
constexpr int HWs8 = W8 * H8;      // 3072
constexpr int HWs16 = W16g * H16g; // 768
constexpr int MP = 64;
constexpr int NTH = 256;
constexpr int BPR = WF / MP;                // 8
constexpr int NBLK = 2 * HF * BPR;          // 6144

constexpr int S = 296;      // row stride (ushorts)
constexpr int SD = S / 2;   // 148 dwords

// d_ws layout (ushort elems)
constexpr int OFF_WC = 0;
constexpr int OFF_W1 = 8192;
constexpr int OFF_W2 = 40960;
constexpr int OFF_WP = 73728;
constexpr int OFF_W3 = 90112;
constexpr int OFF_W4 = 122880;
constexpr int OFF_H0 = 155648;   // K padded 260->288
constexpr int OFF_H1 = 229376;
constexpr int OFF_H2 = 262144;
constexpr int SWZ_TOTAL = 270336;
constexpr int OFF_T = SWZ_TOTAL;           // transposed feat1 (bf16 [B][HW][C])
constexpr int NT_ELEMS = 2 * HWs8 * 128;   // 786432

__device__ __forceinline__ unsigned short f2bf(float f) {  // RNE (prep only)
  union { float f; unsigned u; } v; v.f = f;
  unsigned r = (v.u + 0x7fffu + ((v.u >> 16) & 1u)) >> 16;
  return (unsigned short)r;
}
__device__ __forceinline__ float bf2f(unsigned short h) {
  union { unsigned u; float f; } v; v.u = ((unsigned)h) << 16;
  return v.f;
}
__device__ __forceinline__ float bflo(unsigned u) {
  return __builtin_bit_cast(float, u << 16);
}
__device__ __forceinline__ float bfhi(unsigned u) {
  return __builtin_bit_cast(float, u & 0xffff0000u);
}
#if defined(__has_builtin)
#if __has_builtin(__builtin_amdgcn_cvt_pk_bf16_f32)
#define HAS_PK_BF16 1
#endif
#endif
__device__ __forceinline__ unsigned pack2bf(float a, float b) {
#ifdef HAS_PK_BF16
  typedef __bf16 bf2_t __attribute__((ext_vector_type(2)));
  bf2_t r = __builtin_amdgcn_cvt_pk_bf16_f32(a, b);
  return __builtin_bit_cast(unsigned, r);
#else
  unsigned ua = __builtin_bit_cast(unsigned, a) + 0x8000u;
  unsigned ub = __builtin_bit_cast(unsigned, b) + 0x8000u;
  return __builtin_amdgcn_perm(ub, ua, 0x07060302u);
#endif
}
// gelu via A&S 7.1.26 erf approx (|err| <= 1.5e-7 abs)
__device__ __forceinline__ float gelu_fast(float x) {
  float ax = fabsf(x);
  float z = ax * 0.7071067811865475f;
  float t = __builtin_amdgcn_rcpf(fmaf(0.3275911f, z, 1.0f));
  float poly = fmaf(fmaf(fmaf(fmaf(1.061405429f, t, -1.453152027f), t,
                              1.421413741f), t, -0.284496736f), t, 0.254829592f);
  float y = 1.0f - poly * t * __expf(-z * z);
  return 0.5f * (x + ax * y);
}

// ------------------------------- prep kernels ------------------------------
struct PrepParams { const float* W[9]; unsigned short* ws; };

__global__ void prep_kernel(PrepParams pp) {
  const int K_[9]   = {64, 128, 256, 128, 128, 256, 260, 256, 128};
  const int Kp_[9]  = {64, 128, 256, 128, 128, 256, 288, 256, 128};
  const int N_[9]   = {128, 256, 128, 128, 256, 128, 256, 128, 64};
  const int OFF_[9] = {OFF_WC, OFF_W1, OFF_W2, OFF_WP, OFF_W3, OFF_W4, OFF_H0, OFF_H1, OFF_H2};
  for (int e = blockIdx.x * blockDim.x + threadIdx.x; e < SWZ_TOTAL;
       e += gridDim.x * blockDim.x) {
    int L = 0;
#pragma unroll
    for (int i = 1; i < 9; ++i) if (e >= OFF_[i]) L = i;
    int q = e - OFF_[L];
    int j = q & 7;
    int l = (q >> 3) & 63;
    int r = q >> 9;
    int nks = Kp_[L] >> 4;
    int ks = r % nks;
    int mt = r / nks;
    int n = mt * 32 + (l & 31);
    int k = ks * 16 + ((l >> 5) << 3) + j;
    float v = (k < K_[L]) ? pp.W[L][k * N_[L] + n] : 0.0f;
    pp.ws[e] = f2bf(v);
  }
}

// feat1 [B][C][H][W] fp32 -> ws [B][HW][C] bf16
__global__ void prep2_kernel(const float* __restrict__ f1, unsigned short* wsT) {
  for (int e = blockIdx.x * blockDim.x + threadIdx.x; e < NT_ELEMS;
       e += gridDim.x * blockDim.x) {
    int hw = e % HWs8;
    int c = (e / HWs8) & 127;
    int b = e / (HWs8 * 128);
    wsT[(b * HWs8 + hw) * 128 + c] = f2bf(f1[e]);
  }
}

// ------------------------------ main kernel --------------------------------
struct Params {
  const float* feat_s8; const float* feat_s16;
  const float* ctx_s8;  const float* coarse;
  const float* bc; const float* g1; const float* b1; const float* b2;
  const float* bp; const float* g2; const float* b3; const float* b4;
  const float* h0b; const float* h1b; const float* h2b;
  const float* h3w; const float* h3b;
  const unsigned short* ws;
  const unsigned short* wsT;
  float* out;
};

__device__ __forceinline__ void bilin_setup(float g, int Sg, int& i0, int& i1, float& w) {
  float s = (g + 1.0f) * (0.5f * Sg) - 0.5f;
  float f = floorf(s);
  w = s - f;
  int a = (int)f;
  i0 = min(max(a, 0), Sg - 1);
  i1 = min(max(a + 1, 0), Sg - 1);
}

// Patch index remap into buf's dead columns (float view):
// MAP 0: dword cols [32:64)  (ushort [64:128))   cap 2048 floats
// MAP 1: dword cols [128:144) (ushort [256:288)) cap 1024 floats
template<int MAP>
__device__ __forceinline__ int pmap(int n) {
  if (MAP == 0) return ((n >> 5) * SD) + 32 + (n & 31);
  else          return ((n >> 4) * SD) + 128 + (n & 15);
}

// 32x32x16 MFMA layer, K compile-time (full unroll).
template<int MT, int NT, int EP, bool SYNC, int K>
__device__ __forceinline__ void mfma_layer(
    const unsigned short* __restrict__ Wsw,
    const float* __restrict__ bias,
    const unsigned short* actIn,
    unsigned short* actOut,
    const float* __restrict__ gate,
    const unsigned short* res)
{
  const int t = threadIdx.x;
  const int l = t & 63;
  const int wv = t >> 6;
  constexpr int nks = K >> 4;
  const int mt0 = (NT == 2) ? wv * MT : (wv >> 1);
  const int ntb = (NT == 2) ? 0 : (wv & 1);
  const int lh = l >> 5;
  const int ll = l & 31;

  f32x16 acc[MT][NT];
#pragma unroll
  for (int m = 0; m < MT; ++m) {
#pragma unroll
    for (int g = 0; g < 4; ++g) {
      const int f0 = (mt0 + m) * 32 + g * 8 + (lh << 2);
      const float4 bv = *(const float4*)(bias + f0);
#pragma unroll
      for (int nt = 0; nt < NT; ++nt) {
        acc[m][nt][g * 4 + 0] = bv.x; acc[m][nt][g * 4 + 1] = bv.y;
        acc[m][nt][g * 4 + 2] = bv.z; acc[m][nt][g * 4 + 3] = bv.w;
      }
    }
  }

  const unsigned short* bbase = actIn + (ntb * 32 + ll) * S + (lh << 3);
  const unsigned short* abase = Wsw + (size_t)mt0 * nks * 512 + l * 8;

#pragma unroll
  for (int ks = 0; ks < nks; ++ks) {
    bf16x8 B[NT];
#pragma unroll
    for (int nt = 0; nt < NT; ++nt)
      B[nt] = *(const bf16x8*)(bbase + nt * 32 * S + ks * 16);
#pragma unroll
    for (int m = 0; m < MT; ++m) {
      bf16x8 A = *(const bf16x8*)(abase + (m * nks + ks) * 512);
#pragma unroll
      for (int nt = 0; nt < NT; ++nt)
        acc[m][nt] = __builtin_amdgcn_mfma_f32_32x32x16_bf16(A, B[nt], acc[m][nt], 0, 0, 0);
    }
  }

  if (SYNC) __syncthreads();

#pragma unroll
  for (int m = 0; m < MT; ++m) {
#pragma unroll
    for (int g = 0; g < 4; ++g) {
      const int f0 = (mt0 + m) * 32 + g * 8 + (lh << 2);
      float4 gv;
      if (EP == 3) {
        float4 gg = *(const float4*)(gate + f0);
        gv.x = __builtin_amdgcn_rcpf(1.0f + __expf(-gg.x));
        gv.y = __builtin_amdgcn_rcpf(1.0f + __expf(-gg.y));
        gv.z = __builtin_amdgcn_rcpf(1.0f + __expf(-gg.z));
        gv.w = __builtin_amdgcn_rcpf(1.0f + __expf(-gg.w));
      }
#pragma unroll
      for (int nt = 0; nt < NT; ++nt) {
        const int pt = (ntb + nt) * 32 + ll;
        float v[4];
        v[0] = acc[m][nt][g * 4 + 0]; v[1] = acc[m][nt][g * 4 + 1];
        v[2] = acc[m][nt][g * 4 + 2]; v[3] = acc[m][nt][g * 4 + 3];
        if (EP == 1) {
#pragma unroll
          for (int r = 0; r < 4; ++r) v[r] = gelu_fast(v[r]);
        } else if (EP == 2) {
#pragma unroll
          for (int r = 0; r < 4; ++r) v[r] = fmaxf(v[r], 0.0f);
        } else if (EP == 3) {
          uint2 rv = *(const uint2*)(res + pt * S + f0);
          v[0] = fmaf(gv.x, v[0], bflo(rv.x));
          v[1] = fmaf(gv.y, v[1], bfhi(rv.x));
          v[2] = fmaf(gv.z, v[2], bflo(rv.y));
          v[3] = fmaf(gv.w, v[3], bfhi(rv.y));
        }
        uint2 pk;
        pk.x = pack2bf(v[0], v[1]);
        pk.y = pack2bf(v[2], v[3]);
        *(uint2*)(actOut + pt * S + f0) = pk;
      }
    }
  }
}

// stage a y-lerped patch into a remapped region of buf
template<int NCOL, int NCH, int MAP>
__device__ void stage_patch(const float* __restrict__ fm, int HW, int Wimg,
                            int base, int y0, int y1, float wy, float* bufF)
{
  const int items = NCOL * NCH;
  for (int e = threadIdx.x; e < items; e += NTH) {
    int ch = e / NCOL, col = e - ch * NCOL;
    int ca = min(base + col, Wimg - 1);
    const float* pp = fm + ch * HW;
    float v0 = pp[y0 * Wimg + ca];
    float v1 = pp[y1 * Wimg + ca];
    bufF[pmap<MAP>(col * (NCH + 2) + ch)] = fmaf(wy, v1 - v0, v0);
  }
}

// x-lerp from remapped patch into bf16 B-layout columns of buf
template<int PAIRS, int MAP, int CST>
__device__ void xlerp_tile(const float* __restrict__ bufF, const int* pcB, int shift,
                           const float* wxA, unsigned short* outBuf, int colOff)
{
  const int items = MP * PAIRS;
  for (int it = threadIdx.x; it < items; it += NTH) {
    int pr = it & (PAIRS - 1);
    int pt = it / PAIRS;
    int pc = pcB[pt] >> shift;
    int c0 = pc & 15, c1 = (pc >> 4) & 15;
    float wx = wxA[pt];
    float2 a = *(const float2*)(bufF + pmap<MAP>(c0 * CST + pr * 2));
    float2 b = *(const float2*)(bufF + pmap<MAP>(c1 * CST + pr * 2));
    float r0 = fmaf(wx, b.x - a.x, a.x);
    float r1 = fmaf(wx, b.y - a.y, a.y);
    *(unsigned*)(outBuf + pt * S + colOff + pr * 2) = pack2bf(r0, r1);
  }
}

// coalesced warped gather from transposed bf16 feat1 ([HW][C]); wave = 1 point
__device__ void gather_tile_T(const unsigned short* __restrict__ T,
    const int* offT0, const int* offT1, const float* wxA, const float* wyA,
    unsigned short* outBuf, int colOff)
{
  for (int it = threadIdx.x; it < MP * 64; it += NTH) {
    int pt = it >> 6;
    int c2 = (it & 63) * 2;
    int e0 = offT0[pt], e1 = offT1[pt];
    int du = (e0 & 1) << 7;            // 0 or 128 (channel stride per +1 x)
    int o00 = e0 & ~1, o10 = e1 & ~1;
    float wx = wxA[pt], wy = wyA[pt];
    unsigned a00 = *(const unsigned*)(T + o00 + c2);
    unsigned a01 = *(const unsigned*)(T + o00 + du + c2);
    unsigned a10 = *(const unsigned*)(T + o10 + c2);
    unsigned a11 = *(const unsigned*)(T + o10 + du + c2);
    float w11 = wx * wy;
    float w01 = wx - w11, w10 = wy - w11, w00 = 1.0f - wx - wy + w11;
    float r0 = w00 * bflo(a00) + w01 * bflo(a01) + w10 * bflo(a10) + w11 * bflo(a11);
    float r1 = w00 * bfhi(a00) + w01 * bfhi(a01) + w10 * bfhi(a10) + w11 * bfhi(a11);
    *(unsigned*)(outBuf + pt * S + colOff + c2) = pack2bf(r0, r1);
  }
}

__global__ __launch_bounds__(256, 4)
void ifd_kernel(Params p)
{
  __shared__ __align__(16) unsigned short buf[MP * S];   // 37888 B
  __shared__ int offT0[MP], offT1[MP];                    // 512 B
  __shared__ int pcBoth[MP];                              // 256 B
  __shared__ float w8x[MP], w16x[MP], wWx[MP], wWy[MP];   // 1024 B
  __shared__ float caxA[MP], cayA[MP];                    // 512 B
  __shared__ int uy8_0, uy8_1, uy16_0, uy16_1, ubase8, ubase16;
  __shared__ float uwy8, uwy16;

  float* bufF = (float*)buf;

  const int blk = blockIdx.x;
  const int bb = blk / (HF * BPR);
  const int r = blk % (HF * BPR);
  const int y = r >> 3;
  const int xb = (r & (BPR - 1)) * MP;
  const int t = threadIdx.x;
  const float lim = 1.0f - 1e-6f;

  if (t < MP) {
    const int i = t;
    const int x = xb + i;
    float gx = (x + 0.5f) * (2.0f / WF) - 1.0f;
    float gy = (y + 0.5f) * (2.0f / HF) - 1.0f;
    gx = fminf(fmaxf(gx, -lim), lim);
    gy = fminf(fmaxf(gy, -lim), lim);

    float gx0 = fminf(fmaxf((xb + 0.5f) * (2.0f / WF) - 1.0f, -lim), lim);
    int base8 = min(max((int)floorf((gx0 + 1.0f) * 32.0f - 0.5f), 0), W8 - 1);
    int base16 = min(max((int)floorf((gx0 + 1.0f) * 16.0f - 0.5f), 0), W16g - 1);

    int x0, x1, y0, y1; float wx, wy;
    bilin_setup(gx, W8, x0, x1, wx);
    bilin_setup(gy, H8, y0, y1, wy);
    w8x[i] = wx;
    int o00 = y0 * W8 + x0, o01 = y0 * W8 + x1;
    int o10 = y1 * W8 + x0, o11 = y1 * W8 + x1;

    int a0, a1, b0i, b1i; float vx, vy;
    bilin_setup(gx, W16g, a0, a1, vx);
    bilin_setup(gy, H16g, b0i, b1i, vy);
    w16x[i] = vx;
    pcBoth[i] = (x0 - base8) | ((x1 - base8) << 4)
              | ((a0 - base16) << 8) | ((a1 - base16) << 12);

    if (i == 0) {
      uy8_0 = y0; uy8_1 = y1; uwy8 = wy;
      uy16_0 = b0i; uy16_1 = b1i; uwy16 = vy;
      ubase8 = base8; ubase16 = base16;
    }

    const float* cf = p.coarse + bb * 2 * HWs8;
    float c00 = cf[o00], c01 = cf[o01], c10 = cf[o10], c11 = cf[o11];
    float cx0 = fmaf(wx, c01 - c00, c00), cx1 = fmaf(wx, c11 - c10, c10);
    float cfx = fmaf(wy, cx1 - cx0, cx0);
    const float* cf2 = cf + HWs8;
    c00 = cf2[o00]; c01 = cf2[o01]; c10 = cf2[o10]; c11 = cf2[o11];
    cx0 = fmaf(wx, c01 - c00, c00); cx1 = fmaf(wx, c11 - c10, c10);
    float cfy = fmaf(wy, cx1 - cx0, cx0);
    float cax = cfx * 8.0f, cay = cfy * 8.0f;
    caxA[i] = cax; cayA[i] = cay;

    float wxn = gx + cax * (2.0f / WF);
    float wyn = gy + cay * (2.0f / HF);
    wxn = fminf(fmaxf(wxn, -lim), lim);
    wyn = fminf(fmaxf(wyn, -lim), lim);
    int u0, u1, v0, v1; float uw, vw;
    bilin_setup(wxn, W8, u0, u1, uw);
    bilin_setup(wyn, H8, v0, v1, vw);
    int du = u1 - u0;   // 0 or 1
    offT0[i] = ((v0 * W8 + u0) << 7) | du;
    offT1[i] = ((v1 * W8 + u0) << 7) | du;
    wWx[i] = uw; wWy[i] = vw;
  }
  __syncthreads();

  // stage f8 -> MAP0; ctx -> MAP1
  stage_patch<10, 128, 0>(p.feat_s8 + bb * 128 * HWs8, HWs8, W8,
                          ubase8, uy8_0, uy8_1, uwy8, bufF);
  stage_patch<10, 64, 1>(p.ctx_s8 + bb * 64 * HWs8, HWs8, W8,
                         ubase8, uy8_0, uy8_1, uwy8, bufF);
  __syncthreads();
  xlerp_tile<64, 0, 130>(bufF, pcBoth, 0, w8x, buf, 128);  // f8  -> [128:256)
  xlerp_tile<32, 1, 66>(bufF, pcBoth, 0, w8x, buf, 0);     // ctx -> [0:64)
  __syncthreads();

  // Wc: [0:64) K=64 -> [128:256), residual same cols
  mfma_layer<1, 2, 3, false, 64>(p.ws + OFF_WC, p.bc, buf, buf + 128, p.g1, buf + 128);
  // overlap: stage f16 patch -> MAP1
  stage_patch<6, 128, 1>(p.feat_s16 + bb * 128 * HWs16, HWs16, W16g,
                         ubase16, uy16_0, uy16_1, uwy16, bufF);
  __syncthreads();
  // W1: [128:256) K=128 -> [0:256)
  mfma_layer<2, 2, 1, true, 128>(p.ws + OFF_W1, p.b1, buf + 128, buf, nullptr, nullptr);
  __syncthreads();
  // W2: [0:256) K=256 -> [0:128); then f16 x-lerp -> [128:256)
  mfma_layer<1, 2, 0, true, 256>(p.ws + OFF_W2, p.b2, buf, buf, nullptr, nullptr);
  xlerp_tile<64, 1, 130>(bufF, pcBoth, 8, w16x, buf, 128);
  __syncthreads();
  // Wp: [0:128) -> [128:256), residual same cols
  mfma_layer<1, 2, 3, false, 128>(p.ws + OFF_WP, p.bp, buf, buf + 128, p.g2, buf + 128);
  __syncthreads();
  // W3: [128:256) K=128 -> [0:256)
  mfma_layer<2, 2, 1, true, 128>(p.ws + OFF_W3, p.b3, buf + 128, buf, nullptr, nullptr);
  __syncthreads();
  // W4: [0:256) K=256 -> [0:128); gather -> [128:256); extras -> [256:288)
  mfma_layer<1, 2, 0, true, 256>(p.ws + OFF_W4, p.b4, buf, buf, nullptr, nullptr);
  gather_tile_T(p.wsT + bb * HWs8 * 128, offT0, offT1, wWx, wWy, buf, 128);
  for (int idx = t; idx < MP * 16; idx += NTH) {
    int row = idx >> 4, c = idx & 15;
    unsigned val = 0;
    if (c == 0) {
      float gx = fminf(fmaxf((xb + row + 0.5f) * (2.0f / WF) - 1.0f, -lim), lim);
      float gy = fminf(fmaxf((y + 0.5f) * (2.0f / HF) - 1.0f, -lim), lim);
      val = pack2bf(gx, gy);
    } else if (c == 1) {
      val = pack2bf(caxA[row] * (1.0f / WF), cayA[row] * (1.0f / HF));
    }
    *(unsigned*)(buf + row * S + 256 + c * 2) = val;
  }
  __syncthreads();
  // flow head, all in-place
  mfma_layer<2, 2, 2, true, 288>(p.ws + OFF_H0, p.h0b, buf, buf, nullptr, nullptr);
  __syncthreads();
  mfma_layer<1, 2, 2, true, 256>(p.ws + OFF_H1, p.h1b, buf, buf, nullptr, nullptr);
  __syncthreads();
  mfma_layer<1, 1, 2, true, 128>(p.ws + OFF_H2, p.h2b, buf, buf, nullptr, nullptr);
  __syncthreads();

  // final 64->2 + output (fp32); h3w from global (L2-hot)
  if (t < 128) {
    int i = t & 63, comp = t >> 6;
    float acc = p.h3b[comp];
    const unsigned short* rowp = buf + i * S;
    const float* wp = p.h3w + comp;
#pragma unroll
    for (int k8 = 0; k8 < 8; ++k8) {
      uint4 av = *(const uint4*)(rowp + k8 * 8);
      const float* w8p = wp + k8 * 16;
      acc = fmaf(bflo(av.x), w8p[0], acc);
      acc = fmaf(bfhi(av.x), w8p[2], acc);
      acc = fmaf(bflo(av.y), w8p[4], acc);
      acc = fmaf(bfhi(av.y), w8p[6], acc);
      acc = fmaf(bflo(av.z), w8p[8], acc);
      acc = fmaf(bfhi(av.z), w8p[10], acc);
      acc = fmaf(bflo(av.w), w8p[12], acc);
      acc = fmaf(bfhi(av.w), w8p[14], acc);
    }
    float flow = (comp ? cayA[i] : caxA[i]) + acc * (comp ? (float)HF : (float)WF);
    p.out[((bb * 2 + comp) * HF + y) * WF + xb + i] = flow;
  }
}

extern "C" void kernel_launch(void* const* d_in, const int* in_sizes, int n_in,
                              void* d_out, int out_size, void* d_ws, size_t ws_size,
                              hipStream_t stream) {
  PrepParams pp;
  pp.W[0] = (const float*)d_in[6];   // Wc
  pp.W[1] = (const float*)d_in[9];   // W1
  pp.W[2] = (const float*)d_in[11];  // W2
  pp.W[3] = (const float*)d_in[13];  // Wp
  pp.W[4] = (const float*)d_in[16];  // W3
  pp.W[5] = (const float*)d_in[18];  // W4
  pp.W[6] = (const float*)d_in[20];  // hw0
  pp.W[7] = (const float*)d_in[22];  // hw1
  pp.W[8] = (const float*)d_in[24];  // hw2
  pp.ws = (unsigned short*)d_ws;
  hipLaunchKernelGGL(prep_kernel, dim3((SWZ_TOTAL + NTH - 1) / NTH), dim3(NTH), 0, stream, pp);
  hipLaunchKernelGGL(prep2_kernel, dim3(NT_ELEMS / NTH), dim3(NTH), 0, stream,
                     (const float*)d_in[2], (unsigned short*)d_ws + OFF_T);

  Params p;
  p.feat_s8  = (const float*)d_in[1];
  p.feat_s16 = (const float*)d_in[3];
  p.ctx_s8   = (const float*)d_in[4];
  p.coarse   = (const float*)d_in[5];
  p.bc  = (const float*)d_in[7];
  p.g1  = (const float*)d_in[8];
  p.b1  = (const float*)d_in[10];
  p.b2  = (const float*)d_in[12];
  p.bp  = (const float*)d_in[14];
  p.g2  = (const float*)d_in[15];
  p.b3  = (const float*)d_in[17];
  p.b4  = (const float*)d_in[19];
  p.h0b = (const float*)d_in[21];
  p.h1b = (const float*)d_in[23];
  p.h2b = (const float*)d_in[25];
  p.h3w = (const float*)d_in[26];
  p.h3b = (const float*)d_in[27];
  p.ws  = (const unsigned short*)d_ws;
  p.wsT = (const unsigned short*)d_ws + OFF_T;
  p.out = (float*)d_out;

  hipLaunchKernelGGL(ifd_kernel, dim3(NBLK), dim3(NTH), 0, stream, p);
}

// Round 9
// 462.130 us; speedup vs baseline: 1.1326x; 1.0347x over previous
//
#include <hip/hip_runtime.h>
#include <math.h>

// ---------------------------------------------------------------------------
// ImplicitFlowDecoder — R9: sigmoid-form tanh-GELU (8 VALU vs 14; |err|~4e-4).
// R8 base: coalesced warped gather (transposed bf16 feat1 in d_ws), K-unrolled
// 32x32x16 MFMA, bias-in-accumulator, in-place single-buffer LDS, 4 blocks/CU.
// ---------------------------------------------------------------------------

typedef short bf16x8 __attribute__((ext_vector_type(8)));
typedef float f32x16 __attribute__((ext_vector_type(16)));

constexpr int W8 = 64, H8 = 48, W16g = 32, H16g = 24, WF = 512, HF = 384;
constexpr int HWs8 = W8 * H8;      // 3072
constexpr int HWs16 = W16g * H16g; // 768
constexpr int MP = 64;
constexpr int NTH = 256;
constexpr int BPR = WF / MP;                // 8
constexpr int NBLK = 2 * HF * BPR;          // 6144

constexpr int S = 296;      // row stride (ushorts)
constexpr int SD = S / 2;   // 148 dwords

// d_ws layout (ushort elems)
constexpr int OFF_WC = 0;
constexpr int OFF_W1 = 8192;
constexpr int OFF_W2 = 40960;
constexpr int OFF_WP = 73728;
constexpr int OFF_W3 = 90112;
constexpr int OFF_W4 = 122880;
constexpr int OFF_H0 = 155648;   // K padded 260->288
constexpr int OFF_H1 = 229376;
constexpr int OFF_H2 = 262144;
constexpr int SWZ_TOTAL = 270336;
constexpr int OFF_T = SWZ_TOTAL;           // transposed feat1 (bf16 [B][HW][C])
constexpr int NT_ELEMS = 2 * HWs8 * 128;   // 786432

__device__ __forceinline__ unsigned short f2bf(float f) {  // RNE (prep only)
  union { float f; unsigned u; } v; v.f = f;
  unsigned r = (v.u + 0x7fffu + ((v.u >> 16) & 1u)) >> 16;
  return (unsigned short)r;
}
__device__ __forceinline__ float bf2f(unsigned short h) {
  union { unsigned u; float f; } v; v.u = ((unsigned)h) << 16;
  return v.f;
}
__device__ __forceinline__ float bflo(unsigned u) {
  return __builtin_bit_cast(float, u << 16);
}
__device__ __forceinline__ float bfhi(unsigned u) {
  return __builtin_bit_cast(float, u & 0xffff0000u);
}
#if defined(__has_builtin)
#if __has_builtin(__builtin_amdgcn_cvt_pk_bf16_f32)
#define HAS_PK_BF16 1
#endif
#endif
__device__ __forceinline__ unsigned pack2bf(float a, float b) {
#ifdef HAS_PK_BF16
  typedef __bf16 bf2_t __attribute__((ext_vector_type(2)));
  bf2_t r = __builtin_amdgcn_cvt_pk_bf16_f32(a, b);
  return __builtin_bit_cast(unsigned, r);
#else
  unsigned ua = __builtin_bit_cast(unsigned, a) + 0x8000u;
  unsigned ub = __builtin_bit_cast(unsigned, b) + 0x8000u;
  return __builtin_amdgcn_perm(ub, ua, 0x07060302u);
#endif
}
// tanh-GELU in sigmoid form: gelu(x) = x * sigmoid(1.59576912*(x + 0.044715x^3))
// = x * rcp(1 + exp(x*(-1.59576912 - 0.07135557*x^2))).  ~8 VALU; |err vs erf
// gelu| ~4e-4 abs — below bf16 activation rounding noise.
__device__ __forceinline__ float gelu_fast(float x) {
  float t = fmaf(x * x, -0.07135557f, -1.59576912f);
  float e = __expf(x * t);
  return x * __builtin_amdgcn_rcpf(1.0f + e);
}

// ------------------------------- prep kernels ------------------------------
struct PrepParams { const float* W[9]; unsigned short* ws; };

__global__ void prep_kernel(PrepParams pp) {
  const int K_[9]   = {64, 128, 256, 128, 128, 256, 260, 256, 128};
  const int Kp_[9]  = {64, 128, 256, 128, 128, 256, 288, 256, 128};
  const int N_[9]   = {128, 256, 128, 128, 256, 128, 256, 128, 64};
  const int OFF_[9] = {OFF_WC, OFF_W1, OFF_W2, OFF_WP, OFF_W3, OFF_W4, OFF_H0, OFF_H1, OFF_H2};
  for (int e = blockIdx.x * blockDim.x + threadIdx.x; e < SWZ_TOTAL;
       e += gridDim.x * blockDim.x) {
    int L = 0;
#pragma unroll
    for (int i = 1; i < 9; ++i) if (e >= OFF_[i]) L = i;
    int q = e - OFF_[L];
    int j = q & 7;
    int l = (q >> 3) & 63;
    int r = q >> 9;
    int nks = Kp_[L] >> 4;
    int ks = r % nks;
    int mt = r / nks;
    int n = mt * 32 + (l & 31);
    int k = ks * 16 + ((l >> 5) << 3) + j;
    float v = (k < K_[L]) ? pp.W[L][k * N_[L] + n] : 0.0f;
    pp.ws[e] = f2bf(v);
  }
}

// feat1 [B][C][H][W] fp32 -> ws [B][HW][C] bf16
__global__ void prep2_kernel(const float* __restrict__ f1, unsigned short* wsT) {
  for (int e = blockIdx.x * blockDim.x + threadIdx.x; e < NT_ELEMS;
       e += gridDim.x * blockDim.x) {
    int hw = e % HWs8;
    int c = (e / HWs8) & 127;
    int b = e / (HWs8 * 128);
    wsT[(b * HWs8 + hw) * 128 + c] = f2bf(f1[e]);
  }
}

// ------------------------------ main kernel --------------------------------
struct Params {
  const float* feat_s8; const float* feat_s16;
  const float* ctx_s8;  const float* coarse;
  const float* bc; const float* g1; const float* b1; const float* b2;
  const float* bp; const float* g2; const float* b3; const float* b4;
  const float* h0b; const float* h1b; const float* h2b;
  const float* h3w; const float* h3b;
  const unsigned short* ws;
  const unsigned short* wsT;
  float* out;
};

__device__ __forceinline__ void bilin_setup(float g, int Sg, int& i0, int& i1, float& w) {
  float s = (g + 1.0f) * (0.5f * Sg) - 0.5f;
  float f = floorf(s);
  w = s - f;
  int a = (int)f;
  i0 = min(max(a, 0), Sg - 1);
  i1 = min(max(a + 1, 0), Sg - 1);
}

// Patch index remap into buf's dead columns (float view):
// MAP 0: dword cols [32:64)  (ushort [64:128))   cap 2048 floats
// MAP 1: dword cols [128:144) (ushort [256:288)) cap 1024 floats
template<int MAP>
__device__ __forceinline__ int pmap(int n) {
  if (MAP == 0) return ((n >> 5) * SD) + 32 + (n & 31);
  else          return ((n >> 4) * SD) + 128 + (n & 15);
}

// 32x32x16 MFMA layer, K compile-time (full unroll).
template<int MT, int NT, int EP, bool SYNC, int K>
__device__ __forceinline__ void mfma_layer(
    const unsigned short* __restrict__ Wsw,
    const float* __restrict__ bias,
    const unsigned short* actIn,
    unsigned short* actOut,
    const float* __restrict__ gate,
    const unsigned short* res)
{
  const int t = threadIdx.x;
  const int l = t & 63;
  const int wv = t >> 6;
  constexpr int nks = K >> 4;
  const int mt0 = (NT == 2) ? wv * MT : (wv >> 1);
  const int ntb = (NT == 2) ? 0 : (wv & 1);
  const int lh = l >> 5;
  const int ll = l & 31;

  f32x16 acc[MT][NT];
#pragma unroll
  for (int m = 0; m < MT; ++m) {
#pragma unroll
    for (int g = 0; g < 4; ++g) {
      const int f0 = (mt0 + m) * 32 + g * 8 + (lh << 2);
      const float4 bv = *(const float4*)(bias + f0);
#pragma unroll
      for (int nt = 0; nt < NT; ++nt) {
        acc[m][nt][g * 4 + 0] = bv.x; acc[m][nt][g * 4 + 1] = bv.y;
        acc[m][nt][g * 4 + 2] = bv.z; acc[m][nt][g * 4 + 3] = bv.w;
      }
    }
  }

  const unsigned short* bbase = actIn + (ntb * 32 + ll) * S + (lh << 3);
  const unsigned short* abase = Wsw + (size_t)mt0 * nks * 512 + l * 8;

#pragma unroll
  for (int ks = 0; ks < nks; ++ks) {
    bf16x8 B[NT];
#pragma unroll
    for (int nt = 0; nt < NT; ++nt)
      B[nt] = *(const bf16x8*)(bbase + nt * 32 * S + ks * 16);
#pragma unroll
    for (int m = 0; m < MT; ++m) {
      bf16x8 A = *(const bf16x8*)(abase + (m * nks + ks) * 512);
#pragma unroll
      for (int nt = 0; nt < NT; ++nt)
        acc[m][nt] = __builtin_amdgcn_mfma_f32_32x32x16_bf16(A, B[nt], acc[m][nt], 0, 0, 0);
    }
  }

  if (SYNC) __syncthreads();

#pragma unroll
  for (int m = 0; m < MT; ++m) {
#pragma unroll
    for (int g = 0; g < 4; ++g) {
      const int f0 = (mt0 + m) * 32 + g * 8 + (lh << 2);
      float4 gv;
      if (EP == 3) {
        float4 gg = *(const float4*)(gate + f0);
        gv.x = __builtin_amdgcn_rcpf(1.0f + __expf(-gg.x));
        gv.y = __builtin_amdgcn_rcpf(1.0f + __expf(-gg.y));
        gv.z = __builtin_amdgcn_rcpf(1.0f + __expf(-gg.z));
        gv.w = __builtin_amdgcn_rcpf(1.0f + __expf(-gg.w));
      }
#pragma unroll
      for (int nt = 0; nt < NT; ++nt) {
        const int pt = (ntb + nt) * 32 + ll;
        float v[4];
        v[0] = acc[m][nt][g * 4 + 0]; v[1] = acc[m][nt][g * 4 + 1];
        v[2] = acc[m][nt][g * 4 + 2]; v[3] = acc[m][nt][g * 4 + 3];
        if (EP == 1) {
#pragma unroll
          for (int r = 0; r < 4; ++r) v[r] = gelu_fast(v[r]);
        } else if (EP == 2) {
#pragma unroll
          for (int r = 0; r < 4; ++r) v[r] = fmaxf(v[r], 0.0f);
        } else if (EP == 3) {
          uint2 rv = *(const uint2*)(res + pt * S + f0);
          v[0] = fmaf(gv.x, v[0], bflo(rv.x));
          v[1] = fmaf(gv.y, v[1], bfhi(rv.x));
          v[2] = fmaf(gv.z, v[2], bflo(rv.y));
          v[3] = fmaf(gv.w, v[3], bfhi(rv.y));
        }
        uint2 pk;
        pk.x = pack2bf(v[0], v[1]);
        pk.y = pack2bf(v[2], v[3]);
        *(uint2*)(actOut + pt * S + f0) = pk;
      }
    }
  }
}

// stage a y-lerped patch into a remapped region of buf
template<int NCOL, int NCH, int MAP>
__device__ void stage_patch(const float* __restrict__ fm, int HW, int Wimg,
                            int base, int y0, int y1, float wy, float* bufF)
{
  const int items = NCOL * NCH;
  for (int e = threadIdx.x; e < items; e += NTH) {
    int ch = e / NCOL, col = e - ch * NCOL;
    int ca = min(base + col, Wimg - 1);
    const float* pp = fm + ch * HW;
    float v0 = pp[y0 * Wimg + ca];
    float v1 = pp[y1 * Wimg + ca];
    bufF[pmap<MAP>(col * (NCH + 2) + ch)] = fmaf(wy, v1 - v0, v0);
  }
}

// x-lerp from remapped patch into bf16 B-layout columns of buf
template<int PAIRS, int MAP, int CST>
__device__ void xlerp_tile(const float* __restrict__ bufF, const int* pcB, int shift,
                           const float* wxA, unsigned short* outBuf, int colOff)
{
  const int items = MP * PAIRS;
  for (int it = threadIdx.x; it < items; it += NTH) {
    int pr = it & (PAIRS - 1);
    int pt = it / PAIRS;
    int pc = pcB[pt] >> shift;
    int c0 = pc & 15, c1 = (pc >> 4) & 15;
    float wx = wxA[pt];
    float2 a = *(const float2*)(bufF + pmap<MAP>(c0 * CST + pr * 2));
    float2 b = *(const float2*)(bufF + pmap<MAP>(c1 * CST + pr * 2));
    float r0 = fmaf(wx, b.x - a.x, a.x);
    float r1 = fmaf(wx, b.y - a.y, a.y);
    *(unsigned*)(outBuf + pt * S + colOff + pr * 2) = pack2bf(r0, r1);
  }
}

// coalesced warped gather from transposed bf16 feat1 ([HW][C]); wave = 1 point
__device__ void gather_tile_T(const unsigned short* __restrict__ T,
    const int* offT0, const int* offT1, const float* wxA, const float* wyA,
    unsigned short* outBuf, int colOff)
{
  for (int it = threadIdx.x; it < MP * 64; it += NTH) {
    int pt = it >> 6;
    int c2 = (it & 63) * 2;
    int e0 = offT0[pt], e1 = offT1[pt];
    int du = (e0 & 1) << 7;            // 0 or 128 (channel stride per +1 x)
    int o00 = e0 & ~1, o10 = e1 & ~1;
    float wx = wxA[pt], wy = wyA[pt];
    unsigned a00 = *(const unsigned*)(T + o00 + c2);
    unsigned a01 = *(const unsigned*)(T + o00 + du + c2);
    unsigned a10 = *(const unsigned*)(T + o10 + c2);
    unsigned a11 = *(const unsigned*)(T + o10 + du + c2);
    float w11 = wx * wy;
    float w01 = wx - w11, w10 = wy - w11, w00 = 1.0f - wx - wy + w11;
    float r0 = w00 * bflo(a00) + w01 * bflo(a01) + w10 * bflo(a10) + w11 * bflo(a11);
    float r1 = w00 * bfhi(a00) + w01 * bfhi(a01) + w10 * bfhi(a10) + w11 * bfhi(a11);
    *(unsigned*)(outBuf + pt * S + colOff + c2) = pack2bf(r0, r1);
  }
}

__global__ __launch_bounds__(256, 4)
void ifd_kernel(Params p)
{
  __shared__ __align__(16) unsigned short buf[MP * S];   // 37888 B
  __shared__ int offT0[MP], offT1[MP];                    // 512 B
  __shared__ int pcBoth[MP];                              // 256 B
  __shared__ float w8x[MP], w16x[MP], wWx[MP], wWy[MP];   // 1024 B
  __shared__ float caxA[MP], cayA[MP];                    // 512 B
  __shared__ int uy8_0, uy8_1, uy16_0, uy16_1, ubase8, ubase16;
  __shared__ float uwy8, uwy16;

  float* bufF = (float*)buf;

  const int blk = blockIdx.x;
  const int bb = blk / (HF * BPR);
  const int r = blk % (HF * BPR);
  const int y = r >> 3;
  const int xb = (r & (BPR - 1)) * MP;
  const int t = threadIdx.x;
  const float lim = 1.0f - 1e-6f;

  if (t < MP) {
    const int i = t;
    const int x = xb + i;
    float gx = (x + 0.5f) * (2.0f / WF) - 1.0f;
    float gy = (y + 0.5f) * (2.0f / HF) - 1.0f;
    gx = fminf(fmaxf(gx, -lim), lim);
    gy = fminf(fmaxf(gy, -lim), lim);

    float gx0 = fminf(fmaxf((xb + 0.5f) * (2.0f / WF) - 1.0f, -lim), lim);
    int base8 = min(max((int)floorf((gx0 + 1.0f) * 32.0f - 0.5f), 0), W8 - 1);
    int base16 = min(max((int)floorf((gx0 + 1.0f) * 16.0f - 0.5f), 0), W16g - 1);

    int x0, x1, y0, y1; float wx, wy;
    bilin_setup(gx, W8, x0, x1, wx);
    bilin_setup(gy, H8, y0, y1, wy);
    w8x[i] = wx;
    int o00 = y0 * W8 + x0, o01 = y0 * W8 + x1;
    int o10 = y1 * W8 + x0, o11 = y1 * W8 + x1;

    int a0, a1, b0i, b1i; float vx, vy;
    bilin_setup(gx, W16g, a0, a1, vx);
    bilin_setup(gy, H16g, b0i, b1i, vy);
    w16x[i] = vx;
    pcBoth[i] = (x0 - base8) | ((x1 - base8) << 4)
              | ((a0 - base16) << 8) | ((a1 - base16) << 12);

    if (i == 0) {
      uy8_0 = y0; uy8_1 = y1; uwy8 = wy;
      uy16_0 = b0i; uy16_1 = b1i; uwy16 = vy;
      ubase8 = base8; ubase16 = base16;
    }

    const float* cf = p.coarse + bb * 2 * HWs8;
    float c00 = cf[o00], c01 = cf[o01], c10 = cf[o10], c11 = cf[o11];
    float cx0 = fmaf(wx, c01 - c00, c00), cx1 = fmaf(wx, c11 - c10, c10);
    float cfx = fmaf(wy, cx1 - cx0, cx0);
    const float* cf2 = cf + HWs8;
    c00 = cf2[o00]; c01 = cf2[o01]; c10 = cf2[o10]; c11 = cf2[o11];
    cx0 = fmaf(wx, c01 - c00, c00); cx1 = fmaf(wx, c11 - c10, c10);
    float cfy = fmaf(wy, cx1 - cx0, cx0);
    float cax = cfx * 8.0f, cay = cfy * 8.0f;
    caxA[i] = cax; cayA[i] = cay;

    float wxn = gx + cax * (2.0f / WF);
    float wyn = gy + cay * (2.0f / HF);
    wxn = fminf(fmaxf(wxn, -lim), lim);
    wyn = fminf(fmaxf(wyn, -lim), lim);
    int u0, u1, v0, v1; float uw, vw;
    bilin_setup(wxn, W8, u0, u1, uw);
    bilin_setup(wyn, H8, v0, v1, vw);
    int du = u1 - u0;   // 0 or 1
    offT0[i] = ((v0 * W8 + u0) << 7) | du;
    offT1[i] = ((v1 * W8 + u0) << 7) | du;
    wWx[i] = uw; wWy[i] = vw;
  }
  __syncthreads();

  // stage f8 -> MAP0; ctx -> MAP1
  stage_patch<10, 128, 0>(p.feat_s8 + bb * 128 * HWs8, HWs8, W8,
                          ubase8, uy8_0, uy8_1, uwy8, bufF);
  stage_patch<10, 64, 1>(p.ctx_s8 + bb * 64 * HWs8, HWs8, W8,
                         ubase8, uy8_0, uy8_1, uwy8, bufF);
  __syncthreads();
  xlerp_tile<64, 0, 130>(bufF, pcBoth, 0, w8x, buf, 128);  // f8  -> [128:256)
  xlerp_tile<32, 1, 66>(bufF, pcBoth, 0, w8x, buf, 0);     // ctx -> [0:64)
  __syncthreads();

  // Wc: [0:64) K=64 -> [128:256), residual same cols
  mfma_layer<1, 2, 3, false, 64>(p.ws + OFF_WC, p.bc, buf, buf + 128, p.g1, buf + 128);
  // overlap: stage f16 patch -> MAP1
  stage_patch<6, 128, 1>(p.feat_s16 + bb * 128 * HWs16, HWs16, W16g,
                         ubase16, uy16_0, uy16_1, uwy16, bufF);
  __syncthreads();
  // W1: [128:256) K=128 -> [0:256)
  mfma_layer<2, 2, 1, true, 128>(p.ws + OFF_W1, p.b1, buf + 128, buf, nullptr, nullptr);
  __syncthreads();
  // W2: [0:256) K=256 -> [0:128); then f16 x-lerp -> [128:256)
  mfma_layer<1, 2, 0, true, 256>(p.ws + OFF_W2, p.b2, buf, buf, nullptr, nullptr);
  xlerp_tile<64, 1, 130>(bufF, pcBoth, 8, w16x, buf, 128);
  __syncthreads();
  // Wp: [0:128) -> [128:256), residual same cols
  mfma_layer<1, 2, 3, false, 128>(p.ws + OFF_WP, p.bp, buf, buf + 128, p.g2, buf + 128);
  __syncthreads();
  // W3: [128:256) K=128 -> [0:256)
  mfma_layer<2, 2, 1, true, 128>(p.ws + OFF_W3, p.b3, buf + 128, buf, nullptr, nullptr);
  __syncthreads();
  // W4: [0:256) K=256 -> [0:128); gather -> [128:256); extras -> [256:288)
  mfma_layer<1, 2, 0, true, 256>(p.ws + OFF_W4, p.b4, buf, buf, nullptr, nullptr);
  gather_tile_T(p.wsT + bb * HWs8 * 128, offT0, offT1, wWx, wWy, buf, 128);
  for (int idx = t; idx < MP * 16; idx += NTH) {
    int row = idx >> 4, c = idx & 15;
    unsigned val = 0;
    if (c == 0) {
      float gx = fminf(fmaxf((xb + row + 0.5f) * (2.0f / WF) - 1.0f, -lim), lim);
      float gy = fminf(fmaxf((y + 0.5f) * (2.0f / HF) - 1.0f, -lim), lim);
      val = pack2bf(gx, gy);
    } else if (c == 1) {
      val = pack2bf(caxA[row] * (1.0f / WF), cayA[row] * (1.0f / HF));
    }
    *(unsigned*)(buf + row * S + 256 + c * 2) = val;
  }
  __syncthreads();
  // flow head, all in-place
  mfma_layer<2, 2, 2, true, 288>(p.ws + OFF_H0, p.h0b, buf, buf, nullptr, nullptr);
  __syncthreads();
  mfma_layer<1, 2, 2, true, 256>(p.ws + OFF_H1, p.h1b, buf, buf, nullptr, nullptr);
  __syncthreads();
  mfma_layer<1, 1, 2, true, 128>(p.ws + OFF_H2, p.h2b, buf, buf, nullptr, nullptr);
  __syncthreads();

  // final 64->2 + output (fp32); h3w from global (L2-hot)
  if (t < 128) {
    int i = t & 63, comp = t >> 6;
    float acc = p.h3b[comp];
    const unsigned short* rowp = buf + i * S;
    const float* wp = p.h3w + comp;
#pragma unroll
    for (int k8 = 0; k8 < 8; ++k8) {
      uint4 av = *(const uint4*)(rowp + k8 * 8);
      const float* w8p = wp + k8 * 16;
      acc = fmaf(bflo(av.x), w8p[0], acc);
      acc = fmaf(bfhi(av.x), w8p[2], acc);
      acc = fmaf(bflo(av.y), w8p[4], acc);
      acc = fmaf(bfhi(av.y), w8p[6], acc);
      acc = fmaf(bflo(av.z), w8p[8], acc);
      acc = fmaf(bfhi(av.z), w8p[10], acc);
      acc = fmaf(bflo(av.w), w8p[12], acc);
      acc = fmaf(bfhi(av.w), w8p[14], acc);
    }
    float flow = (comp ? cayA[i] : caxA[i]) + acc * (comp ? (float)HF : (float)WF);
    p.out[((bb * 2 + comp) * HF + y) * WF + xb + i] = flow;
  }
}

extern "C" void kernel_launch(void* const* d_in, const int* in_sizes, int n_in,
                              void* d_out, int out_size, void* d_ws, size_t ws_size,
                              hipStream_t stream) {
  PrepParams pp;
  pp.W[0] = (const float*)d_in[6];   // Wc
  pp.W[1] = (const float*)d_in[9];   // W1
  pp.W[2] = (const float*)d_in[11];  // W2
  pp.W[3] = (const float*)d_in[13];  // Wp
  pp.W[4] = (const float*)d_in[16];  // W3
  pp.W[5] = (const float*)d_in[18];  // W4
  pp.W[6] = (const float*)d_in[20];  // hw0
  pp.W[7] = (const float*)d_in[22];  // hw1
  pp.W[8] = (const float*)d_in[24];  // hw2
  pp.ws = (unsigned short*)d_ws;
  hipLaunchKernelGGL(prep_kernel, dim3((SWZ_TOTAL + NTH - 1) / NTH), dim3(NTH), 0, stream, pp);
  hipLaunchKernelGGL(prep2_kernel, dim3(NT_ELEMS / NTH), dim3(NTH), 0, stream,
                     (const float*)d_in[2], (unsigned short*)d_ws + OFF_T);

  Params p;
  p.feat_s8  = (const float*)d_in[1];
  p.feat_s16 = (const float*)d_in[3];
  p.ctx_s8   = (const float*)d_in[4];
  p.coarse   = (const float*)d_in[5];
  p.bc  = (const float*)d_in[7];
  p.g1  = (const float*)d_in[8];
  p.b1  = (const float*)d_in[10];
  p.b2  = (const float*)d_in[12];
  p.bp  = (const float*)d_in[14];
  p.g2  = (const float*)d_in[15];
  p.b3  = (const float*)d_in[17];
  p.b4  = (const float*)d_in[19];
  p.h0b = (const float*)d_in[21];
  p.h1b = (const float*)d_in[23];
  p.h2b = (const float*)d_in[25];
  p.h3w = (const float*)d_in[26];
  p.h3b = (const float*)d_in[27];
  p.ws  = (const unsigned short*)d_ws;
  p.wsT = (const unsigned short*)d_ws + OFF_T;
  p.out = (float*)d_out;

  hipLaunchKernelGGL(ifd_kernel, dim3(NBLK), dim3(NTH), 0, stream, p);
}